// Round 6
// baseline (177.417 us; speedup 1.0000x reference)
//
#include <hip/hip_runtime.h>
#include <hip/hip_fp16.h>

typedef _Float16 half8 __attribute__((ext_vector_type(8)));
typedef float f32x4 __attribute__((ext_vector_type(4)));

#define BHSZ 16777216  // 65536 * 256
#define SLOT_BYTES 24576  // A: 128x32 fp32 (16KB) + B: 128x32 fp16 (8KB)
#define B_OFF 16384
#define SBAR() __builtin_amdgcn_s_barrier()
#define SCHEDB() __builtin_amdgcn_sched_barrier(0)

__device__ __forceinline__ void gload16(const void* g, const void* lds) {
  __builtin_amdgcn_global_load_lds((const __attribute__((address_space(1))) void*)g,
                                   (__attribute__((address_space(3))) void*)lds,
                                   16, 0, 0);
}

__device__ __forceinline__ float fast_sigmoid(float z) {
  float e = __builtin_amdgcn_exp2f(-z * 1.4426950408889634f);
  return __builtin_amdgcn_rcpf(1.0f + e);
}

__device__ __forceinline__ float fast_tanh(float z) {
  float a = __builtin_fabsf(z);
  float e = __builtin_amdgcn_exp2f(a * 2.8853900817779268f);
  float t = 1.0f - 2.0f * __builtin_amdgcn_rcpf(1.0f + e);
  return z < 0.0f ? -t : t;
}

// ---------------------------------------------------------------------------
// pack_b: Bp[N'][k] fp16 (B^T, N'-major), gate-interleaved columns:
//   N' = t*64 + g*16 + j -> logical col cl = t*16 + j, gate g (0=f,1=i,2=o,3=c)
// ---------------------------------------------------------------------------
__global__ __launch_bounds__(256) void pack_b(
    const float* __restrict__ Wf, const float* __restrict__ Uf,
    const float* __restrict__ Wi, const float* __restrict__ Ui,
    const float* __restrict__ Wo, const float* __restrict__ Uo,
    const float* __restrict__ Wc, const float* __restrict__ Uc,
    _Float16* __restrict__ Bp) {
  int idx = blockIdx.x * 256 + threadIdx.x;  // [0, 524288)
  int k = idx & 511;
  int Np = idx >> 9;
  int g = (Np >> 4) & 3;
  int cl = ((Np >> 6) << 4) | (Np & 15);
  const float* W;
  const float* U;
  switch (g) {
    case 0: W = Wf; U = Uf; break;
    case 1: W = Wi; U = Ui; break;
    case 2: W = Wo; U = Uo; break;
    default: W = Wc; U = Uc; break;
  }
  float v = (k < 256) ? W[k * 256 + cl] : U[(k - 256) * 256 + cl];
  Bp[idx] = (_Float16)v;
}

// ---------------------------------------------------------------------------
// lstm_fused: BM=128, BN'=128, BK=32 per phase, 256 threads (4 waves 2Mx2N,
// wave tile 64x64, acc 4x4 f32x4 = 64 regs). Counted-vmcnt ring-3 schedule:
//   slot = {A: 128x32 fp32, swizzled 16B slots s^(r&7);
//           B: 64 row-pairs x 128B, chunk i8=(r&1)*4+c swizzled ^(rp&7)}
//   staged entirely by global_load_lds (6 per thread per k-half).
//   Phase j: vmcnt(6) [half j+1 stays in flight], s_barrier, stage(j+2),
//   ds_read + cvt + 16 MFMA. vmcnt drains to 0 only at j=15.
// LDS = 3*24KB = 72KB -> 2 independent blocks/CU (epilogue/prologue overlap).
// grid = 4096; XCD-grouped, bn-fastest (A-panel L2 reuse within XCD).
// ---------------------------------------------------------------------------
__global__ __launch_bounds__(256, 2) void lstm_fused(
    const float* __restrict__ x, const float* __restrict__ h,
    const _Float16* __restrict__ Bp, const float* __restrict__ cin,
    const float* __restrict__ bf_, const float* __restrict__ bi_,
    const float* __restrict__ bo_, const float* __restrict__ bc_,
    float* __restrict__ out) {
  extern __shared__ __align__(16) char smem[];  // 3 * 24576 = 73728 B

  int tid = threadIdx.x;
  int w = tid >> 6, l = tid & 63;
  int l15 = l & 15, lg = l >> 4;
  int wr = w >> 1, wcn = w & 1;

  // XCD grouping: 4096 wgs, 512 per XCD; bn fastest within a chunk.
  int bid = blockIdx.x;
  int wg = (bid & 7) * 512 + (bid >> 3);
  int bm = wg >> 3, bn = wg & 7;

  // --- A staging source offsets (fp32 elems): dest idx -> (row, 16B slot s);
  // content A[r][ (s^(r&7))*4 + kb .. +4 ]
  int fA[4];
#pragma unroll
  for (int p = 0; p < 4; ++p) {
    int idx = p * 256 + tid;
    int r = idx >> 3, s = idx & 7;
    fA[p] = (bm * 128 + r) * 256 + ((s ^ (r & 7)) << 2);
  }
  // --- B staging (fp16 elems): dest idx d -> rowpair rp=d>>3, slot s8=d&7;
  // unswizzled i8 = s8^(rp&7); logical row r = rp*2+(i8>>2), chunk c = i8&3.
  int fB[2];
#pragma unroll
  for (int p = 0; p < 2; ++p) {
    int d = p * 256 + tid;
    int rp = d >> 3, s8 = d & 7;
    int i8 = s8 ^ (rp & 7);
    int r = rp * 2 + (i8 >> 2), c = i8 & 3;
    fB[p] = (bn * 128 + r) * 512 + (c << 3);
  }
  // wave-uniform LDS dest bases (HW adds lane*16)
  int ldsA[4], ldsB[2];
#pragma unroll
  for (int p = 0; p < 4; ++p) ldsA[p] = (p * 256 + w * 64) * 16;
#pragma unroll
  for (int p = 0; p < 2; ++p) ldsB[p] = B_OFF + (p * 256 + w * 64) * 16;

  // --- fragment read byte-offsets within a slot ---
  int offA[4][2], offB[4];
#pragma unroll
  for (int mf = 0; mf < 4; ++mf) {
    int r = wr * 64 + mf * 16 + l15;
#pragma unroll
    for (int b = 0; b < 2; ++b)
      offA[mf][b] = r * 128 + (((lg * 2 + b) ^ (r & 7)) << 4);
  }
#pragma unroll
  for (int nf = 0; nf < 4; ++nf) {
    int r = wcn * 64 + nf * 16 + l15;
    int rp = r >> 1;
    offB[nf] = B_OFF + rp * 128 + (((((r & 1) << 2) | lg) ^ (rp & 7)) << 4);
  }

  f32x4 acc[4][4];
#pragma unroll
  for (int a2 = 0; a2 < 4; ++a2)
#pragma unroll
    for (int b2 = 0; b2 < 4; ++b2)
      acc[a2][b2] = (f32x4){0.f, 0.f, 0.f, 0.f};

  auto stage = [&](int j2) {  // k-half j2 in 0..15 -> slot j2%3
    char* db = smem + (j2 % 3) * SLOT_BYTES;
    const float* sa = (j2 < 8) ? x : h;
    int kb = (j2 & 7) * 32;
#pragma unroll
    for (int p = 0; p < 4; ++p) gload16(sa + fA[p] + kb, db + ldsA[p]);
#pragma unroll
    for (int p = 0; p < 2; ++p) gload16(Bp + fB[p] + j2 * 32, db + ldsB[p]);
  };

  // Prologue: halves 0,1 in flight.
  stage(0);
  stage(1);

#pragma unroll
  for (int j = 0; j < 16; ++j) {
    if (j == 15)
      asm volatile("s_waitcnt vmcnt(0)" ::: "memory");
    else
      asm volatile("s_waitcnt vmcnt(6)" ::: "memory");
    SBAR();
    if (j <= 13) stage(j + 2);

    const char* sb = smem + (j % 3) * SLOT_BYTES;
    half8 bv[4];
#pragma unroll
    for (int nf = 0; nf < 4; ++nf)
      bv[nf] = *reinterpret_cast<const half8*>(sb + offB[nf]);
    f32x4 a0[4], a1[4];
#pragma unroll
    for (int mf = 0; mf < 4; ++mf) {
      a0[mf] = *reinterpret_cast<const f32x4*>(sb + offA[mf][0]);
      a1[mf] = *reinterpret_cast<const f32x4*>(sb + offA[mf][1]);
    }
    __builtin_amdgcn_s_setprio(1);
#pragma unroll
    for (int mf = 0; mf < 4; ++mf) {
      half8 av;
      av[0] = (_Float16)a0[mf][0]; av[1] = (_Float16)a0[mf][1];
      av[2] = (_Float16)a0[mf][2]; av[3] = (_Float16)a0[mf][3];
      av[4] = (_Float16)a1[mf][0]; av[5] = (_Float16)a1[mf][1];
      av[6] = (_Float16)a1[mf][2]; av[7] = (_Float16)a1[mf][3];
#pragma unroll
      for (int nf = 0; nf < 4; ++nf)
        acc[mf][nf] = __builtin_amdgcn_mfma_f32_16x16x32_f16(
            av, bv[nf], acc[mf][nf], 0, 0, 0);
    }
    __builtin_amdgcn_s_setprio(0);
    SCHEDB();
  }

  // --- Epilogue: n-frag == gate (0=f,1=i,2=o,3=c); C/D: col=lane&15,
  // row=(lane>>4)*4+reg.
  int col = (bn * 2 + wcn) * 16 + l15;  // logical column in [0,256)
  float vbf = bf_[col], vbi = bi_[col], vbo = bo_[col], vbc = bc_[col];
#pragma unroll
  for (int mf = 0; mf < 4; ++mf) {
#pragma unroll
    for (int r = 0; r < 4; ++r) {
      long row = (long)(bm * 128 + wr * 64 + mf * 16 + lg * 4 + r);
      float zf = acc[mf][0][r] + vbf;
      float zi = acc[mf][1][r] + vbi;
      float zo = acc[mf][2][r] + vbo;
      float zg = acc[mf][3][r] + vbc;
      float fg = fast_sigmoid(zf);
      float ig = fast_sigmoid(zi);
      float og = fast_sigmoid(zo);
      float gg = fast_tanh(zg);
      float cv = cin[row * 256 + col];
      float cn = cv * fg + gg * ig;
      float hn = og * fast_tanh(cn);
      out[row * 256 + col] = cn;
      out[BHSZ + row * 256 + col] = hn;
    }
  }
}

// ---------------------------------------------------------------------------
extern "C" void kernel_launch(void* const* d_in, const int* in_sizes, int n_in,
                              void* d_out, int out_size, void* d_ws, size_t ws_size,
                              hipStream_t stream) {
  const float* x  = (const float*)d_in[0];
  const float* c  = (const float*)d_in[1];
  const float* h  = (const float*)d_in[2];
  const float* Wi = (const float*)d_in[3];
  const float* Ui = (const float*)d_in[4];
  const float* bi = (const float*)d_in[5];
  const float* Wf = (const float*)d_in[6];
  const float* Uf = (const float*)d_in[7];
  const float* bf = (const float*)d_in[8];
  const float* Wc = (const float*)d_in[9];
  const float* Uc = (const float*)d_in[10];
  const float* bc = (const float*)d_in[11];
  const float* Wo = (const float*)d_in[12];
  const float* Uo = (const float*)d_in[13];
  const float* bo = (const float*)d_in[14];

  _Float16* Bp = (_Float16*)d_ws;  // 1 MB packed weights

  pack_b<<<2048, 256, 0, stream>>>(Wf, Uf, Wi, Ui, Wo, Uo, Wc, Uc, Bp);
  lstm_fused<<<4096, 256, 3 * SLOT_BYTES, stream>>>(x, h, Bp, c, bf, bi, bo,
                                                    bc, (float*)d_out);
}

// Round 8
// 149.146 us; speedup vs baseline: 1.1895x; 1.1895x over previous
//
#include <hip/hip_runtime.h>
#include <hip/hip_fp16.h>

typedef _Float16 half8 __attribute__((ext_vector_type(8)));
typedef _Float16 half4 __attribute__((ext_vector_type(4)));
typedef float f32x4 __attribute__((ext_vector_type(4)));

#define BHSZ 16777216     // 65536 * 256
#define SLOT_BYTES 32768  // A: 256x32 fp16 (16KB) + B: 256x32 fp16 (16KB)
#define B_OFF 16384
#define SBAR() __builtin_amdgcn_s_barrier()
#define WAITL() asm volatile("s_waitcnt lgkmcnt(0)" ::: "memory")

__device__ __forceinline__ void gload16(const void* g, const void* lds) {
  __builtin_amdgcn_global_load_lds((const __attribute__((address_space(1))) void*)g,
                                   (__attribute__((address_space(3))) void*)lds,
                                   16, 0, 0);
}

__device__ __forceinline__ float fast_sigmoid(float z) {
  float e = __builtin_amdgcn_exp2f(-z * 1.4426950408889634f);
  return __builtin_amdgcn_rcpf(1.0f + e);
}

__device__ __forceinline__ float fast_tanh(float z) {
  float a = __builtin_fabsf(z);
  float e = __builtin_amdgcn_exp2f(a * 2.8853900817779268f);
  float t = 1.0f - 2.0f * __builtin_amdgcn_rcpf(1.0f + e);
  return z < 0.0f ? -t : t;
}

// ---------------------------------------------------------------------------
// pack_b: Bp[N'][k] fp16 (B^T, N'-major), gate-interleaved columns:
//   N' = t*64 + g*16 + j -> logical col cl = t*16 + j, gate g (0=f,1=i,2=o,3=c)
// ---------------------------------------------------------------------------
__global__ __launch_bounds__(256) void pack_b(
    const float* __restrict__ Wf, const float* __restrict__ Uf,
    const float* __restrict__ Wi, const float* __restrict__ Ui,
    const float* __restrict__ Wo, const float* __restrict__ Uo,
    const float* __restrict__ Wc, const float* __restrict__ Uc,
    _Float16* __restrict__ Bp) {
  int idx = blockIdx.x * 256 + threadIdx.x;  // [0, 524288)
  int k = idx & 511;
  int Np = idx >> 9;
  int g = (Np >> 4) & 3;
  int cl = ((Np >> 6) << 4) | (Np & 15);
  const float* W;
  const float* U;
  switch (g) {
    case 0: W = Wf; U = Uf; break;
    case 1: W = Wi; U = Ui; break;
    case 2: W = Wo; U = Uo; break;
    default: W = Wc; U = Uc; break;
  }
  float v = (k < 256) ? W[k * 256 + cl] : U[(k - 256) * 256 + cl];
  Bp[idx] = (_Float16)v;
}

// ---------------------------------------------------------------------------
// lstm_fused: BM=256, BN'=256, 512 thr (8 waves 2Mx4N, wave 128x64,
// acc 8x4 f32x4). Ring-3 32KB slots; both operands fp16 in LDS as
// ROWPAIR lines: 128 rowpairs x 128B, 8 chunks of 16B per line,
// chunk = ((r&1)*4 + kchunk) ^ (rp&7).   [r6-verified geometry]
// A: T14 reg-staged (fp32 global -> 16 regs -> cvt once -> ds_write_b64),
//    1-phase flight. B: gload_lds (source-side inverse swz), 2-phase flight.
// Phase j: vmcnt(2) [drains B(j)+A(j+1) regs; B(j+1) stays in flight],
// lgkm, s_barrier, cvt+write slot j+1, issue A(j+2)+B(j+2), compute slot j.
// vmcnt(0) only at j=15. grid = 1024; XCD-grouped, bn-fastest.
// ---------------------------------------------------------------------------
__global__ __launch_bounds__(512, 2) void lstm_fused(
    const float* __restrict__ x, const float* __restrict__ h,
    const _Float16* __restrict__ Bp, const float* __restrict__ cin,
    const float* __restrict__ bf_, const float* __restrict__ bi_,
    const float* __restrict__ bo_, const float* __restrict__ bc_,
    float* __restrict__ out) {
  extern __shared__ __align__(16) char smem[];  // 3 * 32768 = 98304 B

  int tid = threadIdx.x;
  int w = tid >> 6, l = tid & 63;
  int l15 = l & 15, lg = l >> 4;
  int wr = w >> 2, wcn = w & 3;

  // XCD grouping: 1024 wgs, 128 per XCD; bn fastest.
  int bid = blockIdx.x;
  int wg = (bid & 7) * 128 + (bid >> 3);
  int bm = wg >> 2, bn = wg & 3;

  // --- A staging maps: load p covers fp32 row = p*64 + (tid>>3),
  // k = (tid&7)*4 .. +4 (8 lanes/row, coalesced 128B global lines).
  // LDS write: rowpair rp=row>>1 (128B line), chunk
  // c = (((row&1)<<2) | (k>>3)) ^ (rp&7), within-chunk 8B half = tid&1.
  int aRowLo = tid >> 3;  // + p*64
  int aKpos = (tid & 7) * 4;
  int aWoff[4];
#pragma unroll
  for (int p = 0; p < 4; ++p) {
    int row = p * 64 + aRowLo;
    int rp = row >> 1;
    int c = ((((row & 1) << 2) | (aKpos >> 3)) ^ (rp & 7));
    aWoff[p] = rp * 128 + (c << 4) + ((tid & 1) << 3);  // bytes
  }

  // --- B staging source offsets (gload_lds linear dest byte
  // B_OFF + rp*128 + s8*16; content from inverse-swizzled source)
  int fB[2];
#pragma unroll
  for (int p = 0; p < 2; ++p) {
    int d = p * 512 + tid;
    int rp = d >> 3, s8 = d & 7;
    int i8 = s8 ^ (rp & 7);
    int r = rp * 2 + (i8 >> 2), cb = i8 & 3;
    fB[p] = (bn * 256 + r) * 512 + (cb << 3);
  }
  int ldsB[2];
#pragma unroll
  for (int p = 0; p < 2; ++p) ldsB[p] = B_OFF + (p * 512 + w * 64) * 16;

  // --- fragment read byte-offsets (identical rowpair geometry for A and B)
  int offA[8], offB[4];
#pragma unroll
  for (int mf = 0; mf < 8; ++mf) {
    int r = wr * 128 + mf * 16 + l15;
    int rp = r >> 1;
    offA[mf] = rp * 128 + (((((r & 1) << 2) | lg) ^ (rp & 7)) << 4);
  }
#pragma unroll
  for (int nf = 0; nf < 4; ++nf) {
    int r = wcn * 64 + nf * 16 + l15;
    int rp = r >> 1;
    offB[nf] = B_OFF + rp * 128 + (((((r & 1) << 2) | lg) ^ (rp & 7)) << 4);
  }

  f32x4 acc[8][4];
#pragma unroll
  for (int a2 = 0; a2 < 8; ++a2)
#pragma unroll
    for (int b2 = 0; b2 < 4; ++b2)
      acc[a2][b2] = (f32x4){0.f, 0.f, 0.f, 0.f};

  f32x4 aReg[4];  // single in-flight A set

  auto issueA = [&](int t) {
    const float* src = (t < 8) ? x : h;
    int kb = (t & 7) * 32;
#pragma unroll
    for (int p = 0; p < 4; ++p) {
      long row = (long)(bm * 256 + p * 64 + aRowLo);
      aReg[p] = *reinterpret_cast<const f32x4*>(src + row * 256 + kb + aKpos);
    }
  };
  auto issueB = [&](int t) {
    char* db = smem + (t % 3) * SLOT_BYTES;
#pragma unroll
    for (int p = 0; p < 2; ++p)
      gload16(Bp + fB[p] + t * 32, db + ldsB[p]);
  };
  auto writeA = [&](int t) {
    char* db = smem + (t % 3) * SLOT_BYTES;
#pragma unroll
    for (int p = 0; p < 4; ++p) {
      half4 o;
      o[0] = (_Float16)aReg[p][0]; o[1] = (_Float16)aReg[p][1];
      o[2] = (_Float16)aReg[p][2]; o[3] = (_Float16)aReg[p][3];
      *reinterpret_cast<half4*>(db + aWoff[p]) = o;
    }
  };

  // --- Prologue: B(0)+A(0) drained (one-time vmcnt 0), slot 0 written;
  // A(1) regs + B(1) left in flight.
  issueB(0);
  issueA(0);
  asm volatile("s_waitcnt vmcnt(0)" ::: "memory");
  writeA(0);
  issueA(1);
  issueB(1);

#pragma unroll
  for (int j = 0; j < 16; ++j) {
    if (j == 15)
      asm volatile("s_waitcnt vmcnt(0)" ::: "memory");
    else
      asm volatile("s_waitcnt vmcnt(2)" ::: "memory");
    WAITL();
    SBAR();
    if (j <= 14) writeA(j + 1);   // cvt once + 4x ds_write_b64
    if (j <= 13) issueA(j + 2);   // 4x dwordx4 -> regs (1-phase flight)
    if (j <= 13) issueB(j + 2);   // 2x gload_lds (2-phase flight)

    const char* sb = smem + (j % 3) * SLOT_BYTES;
    half8 bv[4];
#pragma unroll
    for (int nf = 0; nf < 4; ++nf)
      bv[nf] = *reinterpret_cast<const half8*>(sb + offB[nf]);
#pragma unroll
    for (int bat = 0; bat < 2; ++bat) {
      half8 av[4];
#pragma unroll
      for (int q = 0; q < 4; ++q)
        av[q] = *reinterpret_cast<const half8*>(sb + offA[bat * 4 + q]);
      __builtin_amdgcn_s_setprio(1);
#pragma unroll
      for (int q = 0; q < 4; ++q)
#pragma unroll
        for (int nf = 0; nf < 4; ++nf)
          acc[bat * 4 + q][nf] = __builtin_amdgcn_mfma_f32_16x16x32_f16(
              av[q], bv[nf], acc[bat * 4 + q][nf], 0, 0, 0);
      __builtin_amdgcn_s_setprio(0);
    }
  }

  // --- Epilogue: n-frag == gate (0=f,1=i,2=o,3=c); C/D: col=lane&15,
  // row=(lane>>4)*4+reg.
  int col = (bn * 4 + wcn) * 16 + l15;  // logical column in [0,256)
  float vbf = bf_[col], vbi = bi_[col], vbo = bo_[col], vbc = bc_[col];
#pragma unroll
  for (int mf = 0; mf < 8; ++mf) {
#pragma unroll
    for (int r = 0; r < 4; ++r) {
      long row = (long)(bm * 256 + wr * 128 + mf * 16 + lg * 4 + r);
      float zf = acc[mf][0][r] + vbf;
      float zi = acc[mf][1][r] + vbi;
      float zo = acc[mf][2][r] + vbo;
      float zg = acc[mf][3][r] + vbc;
      float fg = fast_sigmoid(zf);
      float ig = fast_sigmoid(zi);
      float og = fast_sigmoid(zo);
      float gg = fast_tanh(zg);
      float cv = cin[row * 256 + col];
      float cn = cv * fg + gg * ig;
      float hn = og * fast_tanh(cn);
      out[row * 256 + col] = cn;
      out[BHSZ + row * 256 + col] = hn;
    }
  }
}

// ---------------------------------------------------------------------------
extern "C" void kernel_launch(void* const* d_in, const int* in_sizes, int n_in,
                              void* d_out, int out_size, void* d_ws, size_t ws_size,
                              hipStream_t stream) {
  const float* x  = (const float*)d_in[0];
  const float* c  = (const float*)d_in[1];
  const float* h  = (const float*)d_in[2];
  const float* Wi = (const float*)d_in[3];
  const float* Ui = (const float*)d_in[4];
  const float* bi = (const float*)d_in[5];
  const float* Wf = (const float*)d_in[6];
  const float* Uf = (const float*)d_in[7];
  const float* bf = (const float*)d_in[8];
  const float* Wc = (const float*)d_in[9];
  const float* Uc = (const float*)d_in[10];
  const float* bc = (const float*)d_in[11];
  const float* Wo = (const float*)d_in[12];
  const float* Uo = (const float*)d_in[13];
  const float* bo = (const float*)d_in[14];

  _Float16* Bp = (_Float16*)d_ws;  // 1 MB packed weights

  pack_b<<<2048, 256, 0, stream>>>(Wf, Uf, Wi, Ui, Wo, Uo, Wc, Uc, Bp);
  lstm_fused<<<1024, 512, 3 * SLOT_BYTES, stream>>>(x, h, Bp, c, bf, bi, bo,
                                                    bc, (float*)d_out);
}

// Round 9
// 144.588 us; speedup vs baseline: 1.2271x; 1.0315x over previous
//
#include <hip/hip_runtime.h>
#include <hip/hip_fp16.h>

typedef _Float16 half8 __attribute__((ext_vector_type(8)));
typedef float f32x4 __attribute__((ext_vector_type(4)));

#define BHSZ 16777216  // 65536 * 256
#define A_SLOT 8192    // 128 rows x 32 k fp16 (64 rowpair lines x 128B)
#define B_SLOT 16384   // 256 rows x 32 k fp16 (128 rowpair lines x 128B)
#define B_BASE 16384   // A ring-2 occupies [0, 16384)
#define SBAR() __builtin_amdgcn_s_barrier()
#define SCHEDB() __builtin_amdgcn_sched_barrier(0)
#define WAITL() asm volatile("s_waitcnt lgkmcnt(0)" ::: "memory")

__device__ __forceinline__ void gload16(const void* g, const void* lds) {
  __builtin_amdgcn_global_load_lds((const __attribute__((address_space(1))) void*)g,
                                   (__attribute__((address_space(3))) void*)lds,
                                   16, 0, 0);
}

__device__ __forceinline__ float fast_sigmoid(float z) {
  float e = __builtin_amdgcn_exp2f(-z * 1.4426950408889634f);
  return __builtin_amdgcn_rcpf(1.0f + e);
}

__device__ __forceinline__ float fast_tanh(float z) {
  float a = __builtin_fabsf(z);
  float e = __builtin_amdgcn_exp2f(a * 2.8853900817779268f);
  float t = 1.0f - 2.0f * __builtin_amdgcn_rcpf(1.0f + e);
  return z < 0.0f ? -t : t;
}

// ---------------------------------------------------------------------------
// pack_b: Bp[N'][k] fp16 (B^T, N'-major), gate-interleaved columns:
//   N' = t*64 + g*16 + j -> logical col cl = t*16 + j, gate g (0=f,1=i,2=o,3=c)
// ---------------------------------------------------------------------------
__global__ __launch_bounds__(256) void pack_b(
    const float* __restrict__ Wf, const float* __restrict__ Uf,
    const float* __restrict__ Wi, const float* __restrict__ Ui,
    const float* __restrict__ Wo, const float* __restrict__ Uo,
    const float* __restrict__ Wc, const float* __restrict__ Uc,
    _Float16* __restrict__ Bp) {
  int idx = blockIdx.x * 256 + threadIdx.x;  // [0, 524288)
  int k = idx & 511;
  int Np = idx >> 9;
  int g = (Np >> 4) & 3;
  int cl = ((Np >> 6) << 4) | (Np & 15);
  const float* W;
  const float* U;
  switch (g) {
    case 0: W = Wf; U = Uf; break;
    case 1: W = Wi; U = Ui; break;
    case 2: W = Wo; U = Uo; break;
    default: W = Wc; U = Uc; break;
  }
  float v = (k < 256) ? W[k * 256 + cl] : U[(k - 256) * 256 + cl];
  Bp[idx] = (_Float16)v;
}

// ---------------------------------------------------------------------------
// lstm_fused: BM=128, BN'=256, 256 thr (4 waves 1M x 4N; wave 128x64,
// acc 8x4 f32x4 = 128). TWO blocks co-resident per CU (LDS 64KB, regs<=256)
// -> two independent barrier domains overlap each other's stalls.
// LDS layout (rowpair lines, r8-verified): A ring-2 8KB slots, B ring-3 16KB.
// A: reg-staged (4x dwordx4 fp32 -> cvt once -> 2x ds_write b128), 1-ph flight.
// B: gload_lds (source-side inverse swizzle), 2-phase flight.
// Phase j: vmcnt(4) [drains B(j) + A(j+1) regs; B(j+1)x4 stays in flight],
// lgkm, s_barrier, writeA(j+1), issue A(j+2)+B(j+2), ds_read + 32 MFMA.
// vmcnt(0) only at j=15. grid = 2048 (512 bm x 4 bn); XCD-grouped, bn-fastest.
// ---------------------------------------------------------------------------
__global__ __launch_bounds__(256, 2) void lstm_fused(
    const float* __restrict__ x, const float* __restrict__ h,
    const _Float16* __restrict__ Bp, const float* __restrict__ cin,
    const float* __restrict__ bf_, const float* __restrict__ bi_,
    const float* __restrict__ bo_, const float* __restrict__ bc_,
    float* __restrict__ out) {
  __shared__ __align__(16) char smem[65536];  // 16K A ring-2 + 48K B ring-3

  int tid = threadIdx.x;
  int w = tid >> 6, l = tid & 63;
  int l15 = l & 15, lg = l >> 4;

  // XCD grouping: 2048 wgs, 256 per XCD; bn fastest (4 bn of a bm adjacent).
  int bid = blockIdx.x;
  int wg = (bid & 7) * 256 + (bid >> 3);
  int bm = wg >> 2, bn = wg & 3;

  // --- A staging: thread -> row tid>>1 (0..127), k-quarter (tid&1)*16.
  // Global: 4x f32x4 (64B, coalesced). LDS write: rowpair rp = row>>1,
  // chunks c0,c0+1 where c0 = (row&1)*4 + (tid&1)*2, each ^(rp&7).
  int arow = tid >> 1;
  int akq = (tid & 1) << 4;  // fp32 index
  const float* aSrcX = x + (long)(bm * 128 + arow) * 256 + akq;
  const float* aSrcH = h + (long)(bm * 128 + arow) * 256 + akq;
  int arp = arow >> 1;
  int ac0 = ((arow & 1) << 2) | ((tid & 1) << 1);
  int aW0 = arp * 128 + (((ac0 + 0) ^ (arp & 7)) << 4);
  int aW1 = arp * 128 + (((ac0 + 1) ^ (arp & 7)) << 4);

  // --- B staging source offsets (gload_lds linear dest = rp*128 + s8*16;
  // source inverse-swizzled so read-side XOR sees a clean rowpair layout).
  int fB[4];
#pragma unroll
  for (int p = 0; p < 4; ++p) {
    int d = p * 256 + tid;  // 16B-chunk index in [0,1024)
    int rp = d >> 3, s8 = d & 7;
    int i8 = s8 ^ (rp & 7);
    int r = rp * 2 + (i8 >> 2), cb = i8 & 3;
    fB[p] = (bn * 256 + r) * 512 + (cb << 3);  // fp16 elems
  }
  int ldsB[4];
#pragma unroll
  for (int p = 0; p < 4; ++p) ldsB[p] = (p * 256 + w * 64) * 16;

  // --- fragment read byte-offsets (rowpair geometry, zero-conflict in r8)
  int offA[8], offB[4];
#pragma unroll
  for (int mf = 0; mf < 8; ++mf) {
    int r = mf * 16 + l15;  // all 4 waves share the full 128-row A tile
    int rp = r >> 1;
    offA[mf] = rp * 128 + (((((r & 1) << 2) | lg) ^ (rp & 7)) << 4);
  }
#pragma unroll
  for (int nf = 0; nf < 4; ++nf) {
    int r = w * 64 + nf * 16 + l15;  // wave w owns N'-rows [w*64, w*64+64)
    int rp = r >> 1;
    offB[nf] = rp * 128 + (((((r & 1) << 2) | lg) ^ (rp & 7)) << 4);
  }

  f32x4 acc[8][4];
#pragma unroll
  for (int a2 = 0; a2 < 8; ++a2)
#pragma unroll
    for (int b2 = 0; b2 < 4; ++b2)
      acc[a2][b2] = (f32x4){0.f, 0.f, 0.f, 0.f};

  f32x4 aReg[4];  // one in-flight A set (16 fp32 = 64B/thread)

  auto issueA = [&](int t) {
    const float* src = ((t < 8) ? aSrcX : aSrcH) + (t & 7) * 32;
#pragma unroll
    for (int p = 0; p < 4; ++p)
      aReg[p] = *reinterpret_cast<const f32x4*>(src + p * 4);
  };
  auto issueB = [&](int t) {
    char* db = smem + B_BASE + (t % 3) * B_SLOT;
#pragma unroll
    for (int p = 0; p < 4; ++p)
      gload16(Bp + fB[p] + t * 32, db + ldsB[p]);
  };
  auto writeA = [&](int t) {
    char* db = smem + (t & 1) * A_SLOT;
    half8 h0, h1;
    h0[0] = (_Float16)aReg[0][0]; h0[1] = (_Float16)aReg[0][1];
    h0[2] = (_Float16)aReg[0][2]; h0[3] = (_Float16)aReg[0][3];
    h0[4] = (_Float16)aReg[1][0]; h0[5] = (_Float16)aReg[1][1];
    h0[6] = (_Float16)aReg[1][2]; h0[7] = (_Float16)aReg[1][3];
    h1[0] = (_Float16)aReg[2][0]; h1[1] = (_Float16)aReg[2][1];
    h1[2] = (_Float16)aReg[2][2]; h1[3] = (_Float16)aReg[2][3];
    h1[4] = (_Float16)aReg[3][0]; h1[5] = (_Float16)aReg[3][1];
    h1[6] = (_Float16)aReg[3][2]; h1[7] = (_Float16)aReg[3][3];
    *reinterpret_cast<half8*>(db + aW0) = h0;
    *reinterpret_cast<half8*>(db + aW1) = h1;
  };

  // --- Prologue: tile 0 staged+written; A(1) regs then B(1) in flight
  // (A first so steady-state vmcnt(4) drains A(1) and keeps B(1) flying).
  issueB(0);
  issueA(0);
  asm volatile("s_waitcnt vmcnt(0)" ::: "memory");
  writeA(0);
  issueA(1);
  issueB(1);

#pragma unroll
  for (int j = 0; j < 16; ++j) {
    if (j == 15)
      asm volatile("s_waitcnt vmcnt(0)" ::: "memory");
    else
      asm volatile("s_waitcnt vmcnt(4)" ::: "memory");
    WAITL();
    SBAR();
    SCHEDB();
    if (j <= 14) writeA(j + 1);  // cvt once + 2x ds_write_b128
    if (j <= 13) {
      issueA(j + 2);  // 4x dwordx4 -> regs (1-phase flight)
      issueB(j + 2);  // 4x gload_lds (2-phase flight, crosses barriers)
    }

    const char* sa = smem + (j & 1) * A_SLOT;
    const char* sb = smem + B_BASE + (j % 3) * B_SLOT;
    half8 bv[4];
#pragma unroll
    for (int nf = 0; nf < 4; ++nf)
      bv[nf] = *reinterpret_cast<const half8*>(sb + offB[nf]);
#pragma unroll
    for (int bat = 0; bat < 2; ++bat) {
      half8 av[4];
#pragma unroll
      for (int q = 0; q < 4; ++q)
        av[q] = *reinterpret_cast<const half8*>(sa + offA[bat * 4 + q]);
      __builtin_amdgcn_s_setprio(1);
#pragma unroll
      for (int q = 0; q < 4; ++q)
#pragma unroll
        for (int nf = 0; nf < 4; ++nf)
          acc[bat * 4 + q][nf] = __builtin_amdgcn_mfma_f32_16x16x32_f16(
              av[q], bv[nf], acc[bat * 4 + q][nf], 0, 0, 0);
      __builtin_amdgcn_s_setprio(0);
    }
    SCHEDB();
  }

  // --- Epilogue: n-frag == gate (0=f,1=i,2=o,3=c); C/D: col=lane&15,
  // row=(lane>>4)*4+reg.
  int col = (bn * 4 + w) * 16 + l15;  // logical column in [0,256)
  float vbf = bf_[col], vbi = bi_[col], vbo = bo_[col], vbc = bc_[col];
#pragma unroll
  for (int mf = 0; mf < 8; ++mf) {
#pragma unroll
    for (int r = 0; r < 4; ++r) {
      long row = (long)(bm * 128 + mf * 16 + lg * 4 + r);
      float zf = acc[mf][0][r] + vbf;
      float zi = acc[mf][1][r] + vbi;
      float zo = acc[mf][2][r] + vbo;
      float zg = acc[mf][3][r] + vbc;
      float fg = fast_sigmoid(zf);
      float ig = fast_sigmoid(zi);
      float og = fast_sigmoid(zo);
      float gg = fast_tanh(zg);
      float cv = cin[row * 256 + col];
      float cn = cv * fg + gg * ig;
      float hn = og * fast_tanh(cn);
      out[row * 256 + col] = cn;
      out[BHSZ + row * 256 + col] = hn;
    }
  }
}

// ---------------------------------------------------------------------------
extern "C" void kernel_launch(void* const* d_in, const int* in_sizes, int n_in,
                              void* d_out, int out_size, void* d_ws, size_t ws_size,
                              hipStream_t stream) {
  const float* x  = (const float*)d_in[0];
  const float* c  = (const float*)d_in[1];
  const float* h  = (const float*)d_in[2];
  const float* Wi = (const float*)d_in[3];
  const float* Ui = (const float*)d_in[4];
  const float* bi = (const float*)d_in[5];
  const float* Wf = (const float*)d_in[6];
  const float* Uf = (const float*)d_in[7];
  const float* bf = (const float*)d_in[8];
  const float* Wc = (const float*)d_in[9];
  const float* Uc = (const float*)d_in[10];
  const float* bc = (const float*)d_in[11];
  const float* Wo = (const float*)d_in[12];
  const float* Uo = (const float*)d_in[13];
  const float* bo = (const float*)d_in[14];

  _Float16* Bp = (_Float16*)d_ws;  // 1 MB packed weights

  pack_b<<<2048, 256, 0, stream>>>(Wf, Uf, Wi, Ui, Wo, Uo, Wc, Uc, Bp);
  lstm_fused<<<2048, 256, 0, stream>>>(x, h, Bp, c, bf, bi, bo, bc,
                                       (float*)d_out);
}

// Round 10
// 143.229 us; speedup vs baseline: 1.2387x; 1.0095x over previous
//
#include <hip/hip_runtime.h>
#include <hip/hip_fp16.h>

typedef _Float16 half8 __attribute__((ext_vector_type(8)));
typedef float f32x4 __attribute__((ext_vector_type(4)));

#define BHSZ 16777216  // 65536 * 256

__device__ __forceinline__ void gload16(const void* g, const void* lds) {
  __builtin_amdgcn_global_load_lds((const __attribute__((address_space(1))) void*)g,
                                   (__attribute__((address_space(3))) void*)lds,
                                   16, 0, 0);
}

__device__ __forceinline__ float fast_sigmoid(float z) {
  float e = __builtin_amdgcn_exp2f(-z * 1.4426950408889634f);
  return __builtin_amdgcn_rcpf(1.0f + e);
}

__device__ __forceinline__ float fast_tanh(float z) {
  float a = __builtin_fabsf(z);
  float e = __builtin_amdgcn_exp2f(a * 2.8853900817779268f);
  float t = 1.0f - 2.0f * __builtin_amdgcn_rcpf(1.0f + e);
  return z < 0.0f ? -t : t;
}

// ---------------------------------------------------------------------------
// pack_a: Apk[b][k] fp16, k<256 -> x[b][k], k>=256 -> h[b][k-256]  (r1-verbatim)
// ---------------------------------------------------------------------------
__global__ __launch_bounds__(256) void pack_a(const float* __restrict__ x,
                                              const float* __restrict__ h,
                                              _Float16* __restrict__ Apk) {
  long i = (long)blockIdx.x * 256 + threadIdx.x;
  long e = i * 8;
  int b = (int)(e >> 9);
  int k = (int)(e & 511);
  const float* src = (k < 256) ? (x + (long)b * 256 + k)
                               : (h + (long)b * 256 + (k - 256));
  float4 v0 = reinterpret_cast<const float4*>(src)[0];
  float4 v1 = reinterpret_cast<const float4*>(src)[1];
  half8 o;
  o[0] = (_Float16)v0.x; o[1] = (_Float16)v0.y;
  o[2] = (_Float16)v0.z; o[3] = (_Float16)v0.w;
  o[4] = (_Float16)v1.x; o[5] = (_Float16)v1.y;
  o[6] = (_Float16)v1.z; o[7] = (_Float16)v1.w;
  *reinterpret_cast<half8*>(Apk + e) = o;
}

// ---------------------------------------------------------------------------
// pack_b: Bp[N'][k] fp16 (B^T, N'-major), gate-interleaved columns:
//   N' = t*64 + g*16 + j -> logical col cl = t*16 + j, gate g (0=f,1=i,2=o,3=c)
// ---------------------------------------------------------------------------
__global__ __launch_bounds__(256) void pack_b(
    const float* __restrict__ Wf, const float* __restrict__ Uf,
    const float* __restrict__ Wi, const float* __restrict__ Ui,
    const float* __restrict__ Wo, const float* __restrict__ Uo,
    const float* __restrict__ Wc, const float* __restrict__ Uc,
    _Float16* __restrict__ Bp) {
  int idx = blockIdx.x * 256 + threadIdx.x;  // [0, 524288)
  int k = idx & 511;
  int Np = idx >> 9;
  int g = (Np >> 4) & 3;
  int cl = ((Np >> 6) << 4) | (Np & 15);
  const float* W;
  const float* U;
  switch (g) {
    case 0: W = Wf; U = Uf; break;
    case 1: W = Wi; U = Ui; break;
    case 2: W = Wo; U = Uo; break;
    default: W = Wc; U = Uc; break;
  }
  float v = (k < 256) ? W[k * 256 + cl] : U[(k - 256) * 256 + cl];
  Bp[idx] = (_Float16)v;
}

// ---------------------------------------------------------------------------
// lstm_gemm: 256x256 tile, BK=64, 512 thr (8 waves 2Mx4N; wave 128x64,
// acc 8x4). Pure-fp16 m201-style schedule on packed A (L3-resident):
//   LDS = 2 x 64KB K-tile buffers. Buffer: [A kk0 16K | A kk1 16K |
//   B kk0 16K | B kk1 16K], each 16K region = 256 rows x 32 k in
//   rowpair-line format (128B line, 8 chunks, chunk = ((r&1)*4+kc)^(rp&7))
//   -- r8-verified zero-conflict for both gload_lds dests and frag reads.
//   Per K-tile kt: ONE __syncthreads (vmcnt(0) drains stage loads issued
//   3-4 phases ago = free), then 4 quadrant-phases; phase q stages half-
//   tile q of kt+1 (A halves first = max lead for slow L3 A; B last = L2-hot)
//   and runs 16 MFMA under setprio. No other barriers/waits.
// grid = 1024 (256 bm x 4 bn); XCD-grouped, bn-fastest (A-panel L2 share).
// ---------------------------------------------------------------------------
__global__ __launch_bounds__(512, 2) void lstm_gemm(
    const _Float16* __restrict__ Apk, const _Float16* __restrict__ Bp,
    const float* __restrict__ cin,
    const float* __restrict__ bf_, const float* __restrict__ bi_,
    const float* __restrict__ bo_, const float* __restrict__ bc_,
    float* __restrict__ out) {
  __shared__ __align__(16) char smem[131072];

  int tid = threadIdx.x;
  int w = tid >> 6, l = tid & 63;
  int l15 = l & 15, lg = l >> 4;
  int wr = w >> 2, wcn = w & 3;

  int bid = blockIdx.x;
  int wg = (bid & 7) * 128 + (bid >> 3);
  int bm = wg >> 2, bn = wg & 3;

  // --- staging source map (per-lane): dest chunk d = tid covers one 16B
  // chunk of an 8KB (128-row x 32-k) stage unit. rp = d>>3, s8 = d&7,
  // i8 = s8^(rp&7); source row = 2*rp + (i8>>2) (+hf*128), k = kk*32+(i8&3)*8.
  int rpl = tid >> 3, s8 = tid & 7;
  int i8 = s8 ^ (rpl & 7);
  int rbase = 2 * rpl + (i8 >> 2);  // 0..127
  int csrc = (i8 & 3) * 8;
  long sA = ((long)bm * 256 + rbase) * 512 + csrc;
  long sB = ((long)bn * 256 + rbase) * 512 + csrc;
  int wb1k = w * 1024;  // wave-uniform LDS dest base offset (HW adds lane*16)

  // --- fragment read byte-offsets within a kk-sub region
  int offA[8], offB[4];
#pragma unroll
  for (int mf = 0; mf < 8; ++mf) {
    int r = wr * 128 + mf * 16 + l15;
    int rp = r >> 1;
    offA[mf] = rp * 128 + (((((r & 1) << 2) | lg) ^ (rp & 7)) << 4);
  }
#pragma unroll
  for (int nf = 0; nf < 4; ++nf) {
    int r = wcn * 64 + nf * 16 + l15;
    int rp = r >> 1;
    offB[nf] = 32768 + rp * 128 + (((((r & 1) << 2) | lg) ^ (rp & 7)) << 4);
  }

  f32x4 acc[8][4];
#pragma unroll
  for (int a2 = 0; a2 < 8; ++a2)
#pragma unroll
    for (int b2 = 0; b2 < 4; ++b2)
      acc[a2][b2] = (f32x4){0.f, 0.f, 0.f, 0.f};

  auto stageA = [&](int ktn, int hf, char* dbuf) {
    const _Float16* s0 = Apk + sA + (long)ktn * 64 + (long)hf * 128 * 512;
    gload16(s0, dbuf + hf * 8192 + wb1k);            // kk0 sub
    gload16(s0 + 32, dbuf + 16384 + hf * 8192 + wb1k);  // kk1 sub
  };
  auto stageB = [&](int ktn, int hf, char* dbuf) {
    const _Float16* s0 = Bp + sB + (long)ktn * 64 + (long)hf * 128 * 512;
    gload16(s0, dbuf + 32768 + hf * 8192 + wb1k);
    gload16(s0 + 32, dbuf + 49152 + hf * 8192 + wb1k);
  };

  // --- Prologue: K-tile 0 into buffer 0 (A halves first).
  stageA(0, 0, smem);
  stageA(0, 1, smem);
  stageB(0, 0, smem);
  stageB(0, 1, smem);

#pragma unroll
  for (int kt = 0; kt < 8; ++kt) {
    __syncthreads();  // vmcnt(0)+lgkm(0)+barrier: stage loads are 3-4
                      // phases old (A) / L2-hot (B) -> cheap drain
    const char* rb = smem + (kt & 1) * 65536;
    char* wbuf = smem + ((kt + 1) & 1) * 65536;
    half8 av[4], bv[4];

    // q0: stage A-half0(kt+1); compute mf0-3 x kk0
    if (kt < 7) stageA(kt + 1, 0, wbuf);
#pragma unroll
    for (int nf = 0; nf < 4; ++nf)
      bv[nf] = *reinterpret_cast<const half8*>(rb + offB[nf]);
#pragma unroll
    for (int q = 0; q < 4; ++q)
      av[q] = *reinterpret_cast<const half8*>(rb + offA[q]);
    __builtin_amdgcn_s_setprio(1);
#pragma unroll
    for (int q = 0; q < 4; ++q)
#pragma unroll
      for (int nf = 0; nf < 4; ++nf)
        acc[q][nf] = __builtin_amdgcn_mfma_f32_16x16x32_f16(
            av[q], bv[nf], acc[q][nf], 0, 0, 0);
    __builtin_amdgcn_s_setprio(0);

    // q1: stage A-half1(kt+1); compute mf4-7 x kk0
    if (kt < 7) stageA(kt + 1, 1, wbuf);
#pragma unroll
    for (int q = 0; q < 4; ++q)
      av[q] = *reinterpret_cast<const half8*>(rb + offA[4 + q]);
    __builtin_amdgcn_s_setprio(1);
#pragma unroll
    for (int q = 0; q < 4; ++q)
#pragma unroll
      for (int nf = 0; nf < 4; ++nf)
        acc[4 + q][nf] = __builtin_amdgcn_mfma_f32_16x16x32_f16(
            av[q], bv[nf], acc[4 + q][nf], 0, 0, 0);
    __builtin_amdgcn_s_setprio(0);

    // q2: stage B-half0(kt+1); compute mf0-3 x kk1
    if (kt < 7) stageB(kt + 1, 0, wbuf);
#pragma unroll
    for (int nf = 0; nf < 4; ++nf)
      bv[nf] = *reinterpret_cast<const half8*>(rb + 16384 + offB[nf]);
#pragma unroll
    for (int q = 0; q < 4; ++q)
      av[q] = *reinterpret_cast<const half8*>(rb + 16384 + offA[q]);
    __builtin_amdgcn_s_setprio(1);
#pragma unroll
    for (int q = 0; q < 4; ++q)
#pragma unroll
      for (int nf = 0; nf < 4; ++nf)
        acc[q][nf] = __builtin_amdgcn_mfma_f32_16x16x32_f16(
            av[q], bv[nf], acc[q][nf], 0, 0, 0);
    __builtin_amdgcn_s_setprio(0);

    // q3: stage B-half1(kt+1); compute mf4-7 x kk1
    if (kt < 7) stageB(kt + 1, 1, wbuf);
#pragma unroll
    for (int q = 0; q < 4; ++q)
      av[q] = *reinterpret_cast<const half8*>(rb + 16384 + offA[4 + q]);
    __builtin_amdgcn_s_setprio(1);
#pragma unroll
    for (int q = 0; q < 4; ++q)
#pragma unroll
      for (int nf = 0; nf < 4; ++nf)
        acc[4 + q][nf] = __builtin_amdgcn_mfma_f32_16x16x32_f16(
            av[q], bv[nf], acc[4 + q][nf], 0, 0, 0);
    __builtin_amdgcn_s_setprio(0);
  }

  // --- Epilogue: n-frag == gate (0=f,1=i,2=o,3=c); C/D: col=lane&15,
  // row=(lane>>4)*4+reg.
  int col = (bn * 4 + wcn) * 16 + l15;  // logical column in [0,256)
  float vbf = bf_[col], vbi = bi_[col], vbo = bo_[col], vbc = bc_[col];
#pragma unroll
  for (int mf = 0; mf < 8; ++mf) {
#pragma unroll
    for (int r = 0; r < 4; ++r) {
      long row = (long)(bm * 256 + wr * 128 + mf * 16 + lg * 4 + r);
      float zf = acc[mf][0][r] + vbf;
      float zi = acc[mf][1][r] + vbi;
      float zo = acc[mf][2][r] + vbo;
      float zg = acc[mf][3][r] + vbc;
      float fg = fast_sigmoid(zf);
      float ig = fast_sigmoid(zi);
      float og = fast_sigmoid(zo);
      float gg = fast_tanh(zg);
      float cv = cin[row * 256 + col];
      float cn = cv * fg + gg * ig;
      float hn = og * fast_tanh(cn);
      out[row * 256 + col] = cn;
      out[BHSZ + row * 256 + col] = hn;
    }
  }
}

// ---------------------------------------------------------------------------
extern "C" void kernel_launch(void* const* d_in, const int* in_sizes, int n_in,
                              void* d_out, int out_size, void* d_ws, size_t ws_size,
                              hipStream_t stream) {
  const float* x  = (const float*)d_in[0];
  const float* c  = (const float*)d_in[1];
  const float* h  = (const float*)d_in[2];
  const float* Wi = (const float*)d_in[3];
  const float* Ui = (const float*)d_in[4];
  const float* bi = (const float*)d_in[5];
  const float* Wf = (const float*)d_in[6];
  const float* Uf = (const float*)d_in[7];
  const float* bf = (const float*)d_in[8];
  const float* Wc = (const float*)d_in[9];
  const float* Uc = (const float*)d_in[10];
  const float* bc = (const float*)d_in[11];
  const float* Wo = (const float*)d_in[12];
  const float* Uo = (const float*)d_in[13];
  const float* bo = (const float*)d_in[14];

  _Float16* Apk = (_Float16*)d_ws;                                    // 64 MB
  _Float16* Bp  = (_Float16*)((char*)d_ws + (size_t)65536 * 512 * 2); // 1 MB

  pack_a<<<16384, 256, 0, stream>>>(x, h, Apk);
  pack_b<<<2048, 256, 0, stream>>>(Wf, Uf, Wi, Ui, Wo, Uo, Wc, Uc, Bp);
  lstm_gemm<<<1024, 512, 0, stream>>>(Apk, Bp, c, bf, bi, bo, bc,
                                      (float*)d_out);
}